// Round 1
// baseline (1067.164 us; speedup 1.0000x reference)
//
#include <hip/hip_runtime.h>
#include <hip/hip_bf16.h>

typedef _Float16 f16;
typedef _Float16 f16x8 __attribute__((ext_vector_type(8)));
typedef float f32x4 __attribute__((ext_vector_type(4)));

constexpr int BATCH = 4, C = 512, CQ = 128, N = 4096;
constexpr int FKD = 256; // f(128) + k(128) channels, stacked

// workspace layout (bytes)
constexpr size_t WS_XT   = 0;                                  // f16 [B][N][C]   16 MB
constexpr size_t WS_FK   = WS_XT   + (size_t)BATCH * N * C * 2;    // f16 [B][N][256]  8 MB
constexpr size_t WS_V    = WS_FK   + (size_t)BATCH * N * FKD * 2;  // f16 [B][C][N]   16 MB
constexpr size_t WS_WCAT = WS_V    + (size_t)BATCH * C * N * 2;    // f16 [256][512]
constexpr size_t WS_WL   = WS_WCAT + (size_t)FKD * C * 2;          // f16 [512][512]
constexpr size_t WS_BC   = WS_WL   + (size_t)C * C * 2;            // f32 [256]

// ---------------------------------------------------------------- weights->fp16
__global__ void prep_weights(const float* __restrict__ Wf_w, const float* __restrict__ Wf_b,
                             const float* __restrict__ Wh_w, const float* __restrict__ Wh_b,
                             const float* __restrict__ Wl_w,
                             f16* __restrict__ wcat, f16* __restrict__ wl, float* __restrict__ bcat) {
    int i = blockIdx.x * 256 + threadIdx.x;                 // grid covers C*C
    if (i < FKD * C) {
        int o = i >> 9, c = i & 511;
        float v = (o < CQ) ? Wf_w[o * C + c] : Wh_w[(o - CQ) * C + c];
        wcat[i] = (f16)v;
    }
    if (i < C * C) wl[i] = (f16)Wl_w[i];
    if (i < FKD) bcat[i] = (i < CQ) ? Wf_b[i] : Wh_b[i - CQ];
}

// ---------------------------------------------------------------- x (B,C,N) f32 -> xT (B,N,C) f16
__global__ void transpose_x(const float* __restrict__ x, f16* __restrict__ xt) {
    __shared__ float tile[64][65];
    int gid = blockIdx.x;
    int b = gid >> 9, rem = gid & 511;
    int c0 = (rem >> 6) * 64, n0 = (rem & 63) * 64;
    int t = threadIdx.x;
    int tn = t & 63, tg = t >> 6;
    const float* xp = x + (size_t)b * C * N + (size_t)c0 * N + n0;
#pragma unroll
    for (int r = 0; r < 16; ++r) {
        int cl = tg + r * 4;
        tile[cl][tn] = xp[(size_t)cl * N + tn];
    }
    __syncthreads();
    f16* xo = xt + (size_t)b * N * C + (size_t)n0 * C + c0;
#pragma unroll
    for (int r = 0; r < 16; ++r) {
        int nl = tg + r * 4;
        xo[(size_t)nl * C + tn] = (f16)tile[tn][nl];
    }
}

// ---------------------------------------------------------------- FK projection: FK[b][n][o] = (Wcat @ x[:,n]) + bcat
__global__ void __launch_bounds__(256) proj_fk(const f16* __restrict__ xt, const f16* __restrict__ wcat,
                                               const float* __restrict__ bcat, f16* __restrict__ fk) {
    int wid = blockIdx.x * 4 + (threadIdx.x >> 6);
    int lane = threadIdx.x & 63;
    int li = lane & 15, lg = lane >> 4;
    int b  = wid >> 10;
    int nt = (wid >> 2) & 255;
    int ot = wid & 3;
    int n0 = nt * 16, o0 = ot * 64;
    const f16* ap = xt + (size_t)(b * N + n0 + li) * C + lg * 8;
    const f16* bp = wcat + (size_t)o0 * C + lg * 8;
    f32x4 acc[4] = {};
    for (int ks = 0; ks < 16; ++ks) {
        f16x8 a = *(const f16x8*)(ap + ks * 32);
#pragma unroll
        for (int t = 0; t < 4; ++t) {
            f16x8 bb = *(const f16x8*)(bp + (size_t)(t * 16 + li) * C + ks * 32);
            acc[t] = __builtin_amdgcn_mfma_f32_16x16x32_f16(a, bb, acc[t], 0, 0, 0);
        }
    }
#pragma unroll
    for (int t = 0; t < 4; ++t) {
        int o = o0 + t * 16 + li;
        float bias = bcat[o];
#pragma unroll
        for (int r = 0; r < 4; ++r) {
            int n = n0 + lg * 4 + r;
            fk[(size_t)(b * N + n) * FKD + o] = (f16)(acc[t][r] + bias);
        }
    }
}

// ---------------------------------------------------------------- V projection: V[b][c][n] = (Wl @ x[:,n]) + Wl_b
__global__ void __launch_bounds__(256) proj_v(const f16* __restrict__ xt, const f16* __restrict__ wl,
                                              const float* __restrict__ wlb, f16* __restrict__ v) {
    int wid = blockIdx.x * 4 + (threadIdx.x >> 6);
    int lane = threadIdx.x & 63;
    int li = lane & 15, lg = lane >> 4;
    int b  = wid >> 11;
    int ct = (wid >> 6) & 31;
    int nt = wid & 63;
    int c0 = ct * 16, n0 = nt * 64;
    const f16* ap = wl + (size_t)(c0 + li) * C + lg * 8;
    const f16* bp = xt + (size_t)(b * N + n0) * C + lg * 8;
    f32x4 acc[4] = {};
    for (int ks = 0; ks < 16; ++ks) {
        f16x8 a = *(const f16x8*)(ap + ks * 32);
#pragma unroll
        for (int t = 0; t < 4; ++t) {
            f16x8 bb = *(const f16x8*)(bp + (size_t)(t * 16 + li) * C + ks * 32);
            acc[t] = __builtin_amdgcn_mfma_f32_16x16x32_f16(a, bb, acc[t], 0, 0, 0);
        }
    }
#pragma unroll
    for (int t = 0; t < 4; ++t) {
#pragma unroll
        for (int r = 0; r < 4; ++r) {
            int c = c0 + lg * 4 + r;
            int n = n0 + t * 16 + li;
            v[(size_t)(b * C + c) * N + n] = (f16)(acc[t][r] + wlb[c]);
        }
    }
}

// ---------------------------------------------------------------- flash attention + residual
// wave = (b, 16-query tile, c-quarter). Swapped PV: O[c][i], col i = lane&15 so
// softmax stats (m, l) live per-lane at i = lane&15 after the S LDS-transpose.
__global__ void __launch_bounds__(256) attn(const f16* __restrict__ fk, const f16* __restrict__ v,
                                            const float* __restrict__ x, const float* __restrict__ alphap,
                                            float* __restrict__ out) {
    __shared__ float s_lds[4][16 * 36];
    __shared__ __align__(16) f16 p_lds[4][16 * 32];
    int wv = threadIdx.x >> 6;
    int wid = blockIdx.x * 4 + wv;
    int lane = threadIdx.x & 63;
    int li = lane & 15, lg = lane >> 4;
    int cw = wid & 3;           // c-quarter
    int it = (wid >> 2) & 255;  // query tile
    int b  = wid >> 10;
    int i0 = it * 16;
    int c0 = cw * 128;
    float* sl = s_lds[wv];
    f16*   pl = p_lds[wv];

    // F fragments (A operand of QK^T), held for the whole j loop
    const f16* fptr = fk + (size_t)(b * N + i0 + li) * FKD + lg * 8;
    f16x8 fa[4];
#pragma unroll
    for (int ks = 0; ks < 4; ++ks) fa[ks] = *(const f16x8*)(fptr + ks * 32);

    const f16* kbase = fk + (size_t)(b * N) * FKD + CQ + lg * 8;
    const f16* vbase = v + (size_t)(b * C + c0 + li) * N + lg * 8;

    f32x4 oacc[8] = {};
    float m = -1e30f, l = 0.f;

    for (int j0 = 0; j0 < N; j0 += 32) {
        // S(16i x 32j) = F^T K, two 16-column MFMA tiles
        f32x4 s[2] = {};
#pragma unroll
        for (int jt = 0; jt < 2; ++jt) {
            const f16* kp = kbase + (size_t)(j0 + jt * 16 + li) * FKD;
#pragma unroll
            for (int ks = 0; ks < 4; ++ks) {
                f16x8 kb = *(const f16x8*)(kp + ks * 32);
                s[jt] = __builtin_amdgcn_mfma_f32_16x16x32_f16(fa[ks], kb, s[jt], 0, 0, 0);
            }
        }
        // transpose S through LDS: write D-layout (row=lg*4+r, col=jt*16+li)
#pragma unroll
        for (int jt = 0; jt < 2; ++jt)
#pragma unroll
            for (int r = 0; r < 4; ++r)
                sl[(lg * 4 + r) * 36 + jt * 16 + li] = s[jt][r];
        __syncthreads();
        // read back: this lane owns query row i = li, j = lg*8 + e
        float sv[8];
#pragma unroll
        for (int e = 0; e < 8; ++e) sv[e] = sl[li * 36 + lg * 8 + e];
        float tmax = sv[0];
#pragma unroll
        for (int e = 1; e < 8; ++e) tmax = fmaxf(tmax, sv[e]);
        tmax = fmaxf(tmax, __shfl_xor(tmax, 16));
        tmax = fmaxf(tmax, __shfl_xor(tmax, 32));
        // T13 deferred rescale: skip O-rescale unless max grew past threshold
        if (!__all(tmax <= m + 8.0f)) {
            float mn = fmaxf(m, tmax);
            float sc = __expf(m - mn);
            m = mn;
            l *= sc;
#pragma unroll
            for (int cf = 0; cf < 8; ++cf) oacc[cf] *= sc;
        }
        float p[8], psum = 0.f;
#pragma unroll
        for (int e = 0; e < 8; ++e) { p[e] = __expf(sv[e] - m); psum += p[e]; }
        psum += __shfl_xor(psum, 16);
        psum += __shfl_xor(psum, 32);
        l += psum;
        // P -> fp16 in LDS, true [i][j] layout
#pragma unroll
        for (int e = 0; e < 8; ++e) pl[li * 32 + lg * 8 + e] = (f16)p[e];
        __syncthreads();
        f16x8 pb = *(const f16x8*)(pl + li * 32 + lg * 8);  // B operand: col=i, k=j
        const f16* vp = vbase + j0;
#pragma unroll
        for (int cf = 0; cf < 8; ++cf) {
            f16x8 va = *(const f16x8*)(vp + (size_t)cf * 16 * N);  // A operand: row=c, k=j
            oacc[cf] = __builtin_amdgcn_mfma_f32_16x16x32_f16(va, pb, oacc[cf], 0, 0, 0);
        }
    }
    // epilogue: O[c][i] with i = i0+li -> coalesced over li; + residual
    float alpha = alphap[0];
    float inv = alpha / l;
    const float* xp = x + (size_t)(b * C + c0) * N + i0 + li;
    float* op = out + (size_t)(b * C + c0) * N + i0 + li;
#pragma unroll
    for (int cf = 0; cf < 8; ++cf)
#pragma unroll
        for (int r = 0; r < 4; ++r) {
            int c = cf * 16 + lg * 4 + r;
            op[(size_t)c * N] = oacc[cf][r] * inv + xp[(size_t)c * N];
        }
}

extern "C" void kernel_launch(void* const* d_in, const int* in_sizes, int n_in,
                              void* d_out, int out_size, void* d_ws, size_t ws_size,
                              hipStream_t stream) {
    const float* x     = (const float*)d_in[0];
    const float* Wf_w  = (const float*)d_in[1];
    const float* Wf_b  = (const float*)d_in[2];
    const float* Wh_w  = (const float*)d_in[3];
    const float* Wh_b  = (const float*)d_in[4];
    const float* Wl_w  = (const float*)d_in[5];
    const float* Wl_b  = (const float*)d_in[6];
    const float* alpha = (const float*)d_in[7];
    char* ws = (char*)d_ws;
    f16*   xt   = (f16*)(ws + WS_XT);
    f16*   fkb  = (f16*)(ws + WS_FK);
    f16*   vb   = (f16*)(ws + WS_V);
    f16*   wcat = (f16*)(ws + WS_WCAT);
    f16*   wl   = (f16*)(ws + WS_WL);
    float* bcat = (float*)(ws + WS_BC);
    float* out  = (float*)d_out;

    prep_weights<<<dim3((C * C + 255) / 256), dim3(256), 0, stream>>>(Wf_w, Wf_b, Wh_w, Wh_b, Wl_w, wcat, wl, bcat);
    transpose_x<<<dim3(BATCH * 8 * 64), dim3(256), 0, stream>>>(x, xt);
    proj_fk<<<dim3(1024), dim3(256), 0, stream>>>(xt, wcat, bcat, fkb);
    proj_v<<<dim3(2048), dim3(256), 0, stream>>>(xt, wl, Wl_b, vb);
    attn<<<dim3(1024), dim3(256), 0, stream>>>(fkb, vb, x, alpha, out);
}

// Round 2
// 587.373 us; speedup vs baseline: 1.8168x; 1.8168x over previous
//
#include <hip/hip_runtime.h>
#include <hip/hip_bf16.h>

typedef _Float16 f16;
typedef _Float16 f16x4 __attribute__((ext_vector_type(4)));
typedef _Float16 f16x8 __attribute__((ext_vector_type(8)));
typedef float f32x4 __attribute__((ext_vector_type(4)));

constexpr int BATCH = 4, C = 512, CQ = 128, N = 4096;
constexpr int FKD = 256; // f(128) + k(128) channels, stacked

// workspace layout (bytes)
constexpr size_t WS_XT   = 0;                                      // f16 [B][N][C]   16 MB
constexpr size_t WS_FK   = WS_XT   + (size_t)BATCH * N * C * 2;    // f16 [B][N][256]  8 MB
constexpr size_t WS_V    = WS_FK   + (size_t)BATCH * N * FKD * 2;  // f16 [B][C][N]   16 MB
constexpr size_t WS_WCAT = WS_V    + (size_t)BATCH * C * N * 2;    // f16 [256][512]
constexpr size_t WS_WL   = WS_WCAT + (size_t)FKD * C * 2;          // f16 [512][512]
constexpr size_t WS_BC   = WS_WL   + (size_t)C * C * 2;            // f32 [256]

// ---------------------------------------------------------------- weights->fp16
__global__ void prep_weights(const float* __restrict__ Wf_w, const float* __restrict__ Wf_b,
                             const float* __restrict__ Wh_w, const float* __restrict__ Wh_b,
                             const float* __restrict__ Wl_w,
                             f16* __restrict__ wcat, f16* __restrict__ wl, float* __restrict__ bcat) {
    int i = blockIdx.x * 256 + threadIdx.x;                 // grid covers C*C
    if (i < FKD * C) {
        int o = i >> 9, c = i & 511;
        float v = (o < CQ) ? Wf_w[o * C + c] : Wh_w[(o - CQ) * C + c];
        wcat[i] = (f16)v;
    }
    if (i < C * C) wl[i] = (f16)Wl_w[i];
    if (i < FKD) bcat[i] = (i < CQ) ? Wf_b[i] : Wh_b[i - CQ];
}

// ---------------------------------------------------------------- x (B,C,N) f32 -> xT (B,N,C) f16
__global__ void transpose_x(const float* __restrict__ x, f16* __restrict__ xt) {
    __shared__ float tile[64][65];
    int gid = blockIdx.x;
    int b = gid >> 9, rem = gid & 511;
    int c0 = (rem >> 6) * 64, n0 = (rem & 63) * 64;
    int t = threadIdx.x;
    int tn = t & 63, tg = t >> 6;
    const float* xp = x + (size_t)b * C * N + (size_t)c0 * N + n0;
#pragma unroll
    for (int r = 0; r < 16; ++r) {
        int cl = tg + r * 4;
        tile[cl][tn] = xp[(size_t)cl * N + tn];
    }
    __syncthreads();
    f16* xo = xt + (size_t)b * N * C + (size_t)n0 * C + c0;
#pragma unroll
    for (int r = 0; r < 16; ++r) {
        int nl = tg + r * 4;
        xo[(size_t)nl * C + tn] = (f16)tile[tn][nl];
    }
}

// ---------------------------------------------------------------- FK projection: FK[b][n][o] = (Wcat @ x[:,n]) + bcat
__global__ void __launch_bounds__(256) proj_fk(const f16* __restrict__ xt, const f16* __restrict__ wcat,
                                               const float* __restrict__ bcat, f16* __restrict__ fk) {
    int wid = blockIdx.x * 4 + (threadIdx.x >> 6);
    int lane = threadIdx.x & 63;
    int li = lane & 15, lg = lane >> 4;
    int b  = wid >> 10;
    int nt = (wid >> 2) & 255;
    int ot = wid & 3;
    int n0 = nt * 16, o0 = ot * 64;
    const f16* ap = xt + (size_t)(b * N + n0 + li) * C + lg * 8;
    const f16* bp = wcat + (size_t)o0 * C + lg * 8;
    f32x4 acc[4] = {};
    for (int ks = 0; ks < 16; ++ks) {
        f16x8 a = *(const f16x8*)(ap + ks * 32);
#pragma unroll
        for (int t = 0; t < 4; ++t) {
            f16x8 bb = *(const f16x8*)(bp + (size_t)(t * 16 + li) * C + ks * 32);
            acc[t] = __builtin_amdgcn_mfma_f32_16x16x32_f16(a, bb, acc[t], 0, 0, 0);
        }
    }
#pragma unroll
    for (int t = 0; t < 4; ++t) {
        int o = o0 + t * 16 + li;
        float bias = bcat[o];
#pragma unroll
        for (int r = 0; r < 4; ++r) {
            int n = n0 + lg * 4 + r;
            fk[(size_t)(b * N + n) * FKD + o] = (f16)(acc[t][r] + bias);
        }
    }
}

// ---------------------------------------------------------------- V projection: V[b][c][n] = (Wl @ x[:,n]) + Wl_b
__global__ void __launch_bounds__(256) proj_v(const f16* __restrict__ xt, const f16* __restrict__ wl,
                                              const float* __restrict__ wlb, f16* __restrict__ v) {
    int wid = blockIdx.x * 4 + (threadIdx.x >> 6);
    int lane = threadIdx.x & 63;
    int li = lane & 15, lg = lane >> 4;
    int b  = wid >> 11;
    int ct = (wid >> 6) & 31;
    int nt = wid & 63;
    int c0 = ct * 16, n0 = nt * 64;
    const f16* ap = wl + (size_t)(c0 + li) * C + lg * 8;
    const f16* bp = xt + (size_t)(b * N + n0) * C + lg * 8;
    f32x4 acc[4] = {};
    for (int ks = 0; ks < 16; ++ks) {
        f16x8 a = *(const f16x8*)(ap + ks * 32);
#pragma unroll
        for (int t = 0; t < 4; ++t) {
            f16x8 bb = *(const f16x8*)(bp + (size_t)(t * 16 + li) * C + ks * 32);
            acc[t] = __builtin_amdgcn_mfma_f32_16x16x32_f16(a, bb, acc[t], 0, 0, 0);
        }
    }
#pragma unroll
    for (int t = 0; t < 4; ++t) {
#pragma unroll
        for (int r = 0; r < 4; ++r) {
            int c = c0 + lg * 4 + r;
            int n = n0 + t * 16 + li;
            v[(size_t)(b * C + c) * N + n] = (f16)(acc[t][r] + wlb[c]);
        }
    }
}

// ---------------------------------------------------------------- flash attention + residual (v2)
// Block = 4 waves, same 32-query tile, wave = one c-quarter (128 channels).
// Swapped QK^T: S^T = mfma(A=K, B=F) -> lane holds query i = lane&15 directly;
// softmax fully per-lane + 2 shfl_xor. NO block barriers anywhere: the only LDS
// (P buffer) is wave-private, ordered by compiler lgkmcnt.
__global__ void __launch_bounds__(256) attn(const f16* __restrict__ fk, const f16* __restrict__ v,
                                            const float* __restrict__ x, const float* __restrict__ alphap,
                                            float* __restrict__ out) {
    __shared__ __align__(16) f16 p_lds[4][2][16 * 40];   // [wave][i-frag][row i][32 j + pad 8]
    const int wv = threadIdx.x >> 6;
    const int lane = threadIdx.x & 63;
    const int li = lane & 15, lg = lane >> 4;
    const int cw = wv;                    // c-quarter
    const int it = blockIdx.x & 127;      // 32-query tile
    const int b  = blockIdx.x >> 7;
    const int i0 = it * 32;
    const int c0 = cw * 128;

    // F fragments (B operand of swapped QK): col=i=li, k(ck)=lg*8+e; two i-frags
    f16x8 fb[2][4];
#pragma unroll
    for (int f = 0; f < 2; ++f) {
        const f16* fp = fk + (size_t)(b * N + i0 + f * 16 + li) * FKD + lg * 8;
#pragma unroll
        for (int ks = 0; ks < 4; ++ks) fb[f][ks] = *(const f16x8*)(fp + ks * 32);
    }
    const f16* kbase = fk + (size_t)(b * N) * FKD + CQ + lg * 8;       // A operand: row j, k=ck
    const f16* vbase = v + (size_t)(b * C + c0 + li) * N + lg * 8;     // A operand: row c, k=j

    f32x4 oacc[8][2] = {};                 // [c-frag][i-frag]
    float ms[2] = {-1e30f, -1e30f}, ls[2] = {0.f, 0.f};

    // preload K A-frags for j0 = 0: frag[jt*4+ks] covers rows j=jt*16+li, k=ks*32+lg*8
    f16x8 kf[8];
#pragma unroll
    for (int jt = 0; jt < 2; ++jt)
#pragma unroll
        for (int ks = 0; ks < 4; ++ks)
            kf[jt * 4 + ks] = *(const f16x8*)(kbase + (size_t)(jt * 16 + li) * FKD + ks * 32);

    for (int j0 = 0; j0 < N; j0 += 32) {
        // S^T[j][i] = sum_ck K[j][ck] F[i][ck]
        f32x4 s[2][2] = {};                // [jt][i-frag]
#pragma unroll
        for (int jt = 0; jt < 2; ++jt)
#pragma unroll
            for (int ks = 0; ks < 4; ++ks)
#pragma unroll
                for (int f = 0; f < 2; ++f)
                    s[jt][f] = __builtin_amdgcn_mfma_f32_16x16x32_f16(kf[jt * 4 + ks], fb[f][ks], s[jt][f], 0, 0, 0);

        // issue V loads now: latency hides under the softmax VALU phase
        f16x8 va[8];
        const f16* vp = vbase + j0;
#pragma unroll
        for (int cf = 0; cf < 8; ++cf) va[cf] = *(const f16x8*)(vp + (size_t)cf * 16 * N);

        // prefetch next step's K frags (critical serial dep of next iteration)
        const int jn = (j0 + 32 < N) ? (j0 + 32) : 0;
#pragma unroll
        for (int jt = 0; jt < 2; ++jt)
#pragma unroll
            for (int ks = 0; ks < 4; ++ks)
                kf[jt * 4 + ks] = *(const f16x8*)(kbase + (size_t)(jn + jt * 16 + li) * FKD + ks * 32);

        // online softmax per i-frag; lane owns query i = i0+f*16+li, j = jt*16+lg*4+r
        f16x8 pb[2];
#pragma unroll
        for (int f = 0; f < 2; ++f) {
            float tmax = s[0][f][0];
#pragma unroll
            for (int r = 1; r < 4; ++r) tmax = fmaxf(tmax, s[0][f][r]);
#pragma unroll
            for (int r = 0; r < 4; ++r) tmax = fmaxf(tmax, s[1][f][r]);
            tmax = fmaxf(tmax, __shfl_xor(tmax, 16));
            tmax = fmaxf(tmax, __shfl_xor(tmax, 32));
            float m = ms[f];
            // T13 deferred rescale
            if (!__all(tmax <= m + 8.0f)) {
                float mn = fmaxf(m, tmax);
                float sc = __expf(m - mn);
                ms[f] = mn; m = mn;
                ls[f] *= sc;
#pragma unroll
                for (int cf = 0; cf < 8; ++cf) oacc[cf][f] *= sc;
            }
            float psum = 0.f;
            f16* plf = p_lds[wv][f];
#pragma unroll
            for (int jt = 0; jt < 2; ++jt) {
                f16x4 pkv;
#pragma unroll
                for (int r = 0; r < 4; ++r) {
                    float p = __expf(s[jt][f][r] - m);
                    psum += p;
                    pkv[r] = (f16)p;
                }
                *(f16x4*)(plf + li * 40 + jt * 16 + lg * 4) = pkv;   // P^T[i][j], wave-private
            }
            psum += __shfl_xor(psum, 16);
            psum += __shfl_xor(psum, 32);
            ls[f] += psum;
            pb[f] = *(const f16x8*)(plf + li * 40 + lg * 8);          // B operand: col=i, k=j
        }

        // PV: O[c][i] += V[c][j] P^T[j][i]
#pragma unroll
        for (int cf = 0; cf < 8; ++cf)
#pragma unroll
            for (int f = 0; f < 2; ++f)
                oacc[cf][f] = __builtin_amdgcn_mfma_f32_16x16x32_f16(va[cf], pb[f], oacc[cf][f], 0, 0, 0);
    }

    // epilogue: O[c][i], i = i0 + f*16 + li coalesced over li; + residual
    const float alpha = alphap[0];
    float inv[2] = {alpha / ls[0], alpha / ls[1]};
#pragma unroll
    for (int f = 0; f < 2; ++f) {
        const float* xp = x + (size_t)(b * C + c0) * N + i0 + f * 16 + li;
        float* op = out + (size_t)(b * C + c0) * N + i0 + f * 16 + li;
#pragma unroll
        for (int cf = 0; cf < 8; ++cf)
#pragma unroll
            for (int r = 0; r < 4; ++r) {
                int c = cf * 16 + lg * 4 + r;
                op[(size_t)c * N] = oacc[cf][f][r] * inv[f] + xp[(size_t)c * N];
            }
    }
}

extern "C" void kernel_launch(void* const* d_in, const int* in_sizes, int n_in,
                              void* d_out, int out_size, void* d_ws, size_t ws_size,
                              hipStream_t stream) {
    const float* x     = (const float*)d_in[0];
    const float* Wf_w  = (const float*)d_in[1];
    const float* Wf_b  = (const float*)d_in[2];
    const float* Wh_w  = (const float*)d_in[3];
    const float* Wh_b  = (const float*)d_in[4];
    const float* Wl_w  = (const float*)d_in[5];
    const float* Wl_b  = (const float*)d_in[6];
    const float* alpha = (const float*)d_in[7];
    char* ws = (char*)d_ws;
    f16*   xt   = (f16*)(ws + WS_XT);
    f16*   fkb  = (f16*)(ws + WS_FK);
    f16*   vb   = (f16*)(ws + WS_V);
    f16*   wcat = (f16*)(ws + WS_WCAT);
    f16*   wl   = (f16*)(ws + WS_WL);
    float* bcat = (float*)(ws + WS_BC);
    float* out  = (float*)d_out;

    prep_weights<<<dim3((C * C + 255) / 256), dim3(256), 0, stream>>>(Wf_w, Wf_b, Wh_w, Wh_b, Wl_w, wcat, wl, bcat);
    transpose_x<<<dim3(BATCH * 8 * 64), dim3(256), 0, stream>>>(x, xt);
    proj_fk<<<dim3(1024), dim3(256), 0, stream>>>(xt, wcat, bcat, fkb);
    proj_v<<<dim3(2048), dim3(256), 0, stream>>>(xt, wl, Wl_b, vb);
    // 4 b x 128 query-tiles = 512 blocks; block's 4 waves share the query tile
    attn<<<dim3(512), dim3(256), 0, stream>>>(fkb, vb, x, alpha, out);
}

// Round 3
// 488.454 us; speedup vs baseline: 2.1848x; 1.2025x over previous
//
#include <hip/hip_runtime.h>
#include <hip/hip_bf16.h>

typedef _Float16 f16;
typedef _Float16 f16x4 __attribute__((ext_vector_type(4)));
typedef _Float16 f16x8 __attribute__((ext_vector_type(8)));
typedef float f32x4 __attribute__((ext_vector_type(4)));

constexpr int BATCH = 4, C = 512, CQ = 128, N = 4096;
constexpr int FKD = 256; // f(128) + k(128) channels, stacked

// workspace layout (bytes)
constexpr size_t WS_XT   = 0;                                      // f16 [B][N][C]   16 MB
constexpr size_t WS_FK   = WS_XT   + (size_t)BATCH * N * C * 2;    // f16 [B][N][256]  8 MB
constexpr size_t WS_V    = WS_FK   + (size_t)BATCH * N * FKD * 2;  // f16 [B][C][N]   16 MB
constexpr size_t WS_WCAT = WS_V    + (size_t)BATCH * C * N * 2;    // f16 [256][512]
constexpr size_t WS_WL   = WS_WCAT + (size_t)FKD * C * 2;          // f16 [512][512]
constexpr size_t WS_BC   = WS_WL   + (size_t)C * C * 2;            // f32 [256]

// ---------------------------------------------------------------- weights->fp16
__global__ void prep_weights(const float* __restrict__ Wf_w, const float* __restrict__ Wf_b,
                             const float* __restrict__ Wh_w, const float* __restrict__ Wh_b,
                             const float* __restrict__ Wl_w,
                             f16* __restrict__ wcat, f16* __restrict__ wl, float* __restrict__ bcat) {
    int i = blockIdx.x * 256 + threadIdx.x;                 // grid covers C*C
    if (i < FKD * C) {
        int o = i >> 9, c = i & 511;
        float v = (o < CQ) ? Wf_w[o * C + c] : Wh_w[(o - CQ) * C + c];
        wcat[i] = (f16)v;
    }
    if (i < C * C) wl[i] = (f16)Wl_w[i];
    if (i < FKD) bcat[i] = (i < CQ) ? Wf_b[i] : Wh_b[i - CQ];
}

// ---------------------------------------------------------------- x (B,C,N) f32 -> xT (B,N,C) f16
__global__ void transpose_x(const float* __restrict__ x, f16* __restrict__ xt) {
    __shared__ float tile[64][65];
    int gid = blockIdx.x;
    int b = gid >> 9, rem = gid & 511;
    int c0 = (rem >> 6) * 64, n0 = (rem & 63) * 64;
    int t = threadIdx.x;
    int tn = t & 63, tg = t >> 6;
    const float* xp = x + (size_t)b * C * N + (size_t)c0 * N + n0;
#pragma unroll
    for (int r = 0; r < 16; ++r) {
        int cl = tg + r * 4;
        tile[cl][tn] = xp[(size_t)cl * N + tn];
    }
    __syncthreads();
    f16* xo = xt + (size_t)b * N * C + (size_t)n0 * C + c0;
#pragma unroll
    for (int r = 0; r < 16; ++r) {
        int nl = tg + r * 4;
        xo[(size_t)nl * C + tn] = (f16)tile[tn][nl];
    }
}

// ---------------------------------------------------------------- FK projection: FK[b][n][o] = (Wcat @ x[:,n]) + bcat
__global__ void __launch_bounds__(256) proj_fk(const f16* __restrict__ xt, const f16* __restrict__ wcat,
                                               const float* __restrict__ bcat, f16* __restrict__ fk) {
    int wid = blockIdx.x * 4 + (threadIdx.x >> 6);
    int lane = threadIdx.x & 63;
    int li = lane & 15, lg = lane >> 4;
    int b  = wid >> 10;
    int nt = (wid >> 2) & 255;
    int ot = wid & 3;
    int n0 = nt * 16, o0 = ot * 64;
    const f16* ap = xt + (size_t)(b * N + n0 + li) * C + lg * 8;
    const f16* bp = wcat + (size_t)o0 * C + lg * 8;
    f32x4 acc[4] = {};
    for (int ks = 0; ks < 16; ++ks) {
        f16x8 a = *(const f16x8*)(ap + ks * 32);
#pragma unroll
        for (int t = 0; t < 4; ++t) {
            f16x8 bb = *(const f16x8*)(bp + (size_t)(t * 16 + li) * C + ks * 32);
            acc[t] = __builtin_amdgcn_mfma_f32_16x16x32_f16(a, bb, acc[t], 0, 0, 0);
        }
    }
#pragma unroll
    for (int t = 0; t < 4; ++t) {
        int o = o0 + t * 16 + li;
        float bias = bcat[o];
#pragma unroll
        for (int r = 0; r < 4; ++r) {
            int n = n0 + lg * 4 + r;
            fk[(size_t)(b * N + n) * FKD + o] = (f16)(acc[t][r] + bias);
        }
    }
}

// ---------------------------------------------------------------- V projection: V[b][c][n] = (Wl @ x[:,n]) + Wl_b
__global__ void __launch_bounds__(256) proj_v(const f16* __restrict__ xt, const f16* __restrict__ wl,
                                              const float* __restrict__ wlb, f16* __restrict__ v) {
    int wid = blockIdx.x * 4 + (threadIdx.x >> 6);
    int lane = threadIdx.x & 63;
    int li = lane & 15, lg = lane >> 4;
    int b  = wid >> 11;
    int ct = (wid >> 6) & 31;
    int nt = wid & 63;
    int c0 = ct * 16, n0 = nt * 64;
    const f16* ap = wl + (size_t)(c0 + li) * C + lg * 8;
    const f16* bp = xt + (size_t)(b * N + n0) * C + lg * 8;
    f32x4 acc[4] = {};
    for (int ks = 0; ks < 16; ++ks) {
        f16x8 a = *(const f16x8*)(ap + ks * 32);
#pragma unroll
        for (int t = 0; t < 4; ++t) {
            f16x8 bb = *(const f16x8*)(bp + (size_t)(t * 16 + li) * C + ks * 32);
            acc[t] = __builtin_amdgcn_mfma_f32_16x16x32_f16(a, bb, acc[t], 0, 0, 0);
        }
    }
#pragma unroll
    for (int t = 0; t < 4; ++t) {
#pragma unroll
        for (int r = 0; r < 4; ++r) {
            int c = c0 + lg * 4 + r;
            int n = n0 + t * 16 + li;
            v[(size_t)(b * C + c) * N + n] = (f16)(acc[t][r] + wlb[c]);
        }
    }
}

// ---------------------------------------------------------------- flash attention + residual (v3)
// Block = 8 waves (512 thr), one 32-query tile. Wave w owns c-slice [w*64, w*64+64).
// KVBLK=128: K tile (128j x 128ck, 32KB) LDS-staged double-buffered, XOR-swizzled.
// QK^T computed ONCE per tile: wave w does its 16-j slice; softmax stats exchanged
// via LDS; P (32i x 128j f16, swizzled) shared -> every wave's PV reads same P.
// 2 barriers/iter. Grid 512 blocks = 2 blocks/CU = 16 waves/CU.
__global__ void __launch_bounds__(512, 4) attn(const f16* __restrict__ fk, const f16* __restrict__ v,
                                               const float* __restrict__ x, const float* __restrict__ alphap,
                                               float* __restrict__ out) {
    __shared__ __align__(16) f16 kbuf[2][128 * 128];   // 64 KB, double-buffered K tile
    __shared__ __align__(16) f16 pbuf[32 * 128];       // 8 KB shared P
    __shared__ float smax[8][2][16];
    __shared__ float ssum[8][2][16];

    const int tid  = threadIdx.x;
    const int wv   = tid >> 6;
    const int lane = tid & 63;
    const int li = lane & 15, lg = lane >> 4;
    const int swl = li & 7;
    const int b  = blockIdx.x >> 7;
    const int it = blockIdx.x & 127;
    const int i0 = it * 32;
    const int c0 = wv * 64;

    // F fragments (B operand of swapped QK): col=i, k=ck
    f16x8 fb[2][4];
#pragma unroll
    for (int f = 0; f < 2; ++f) {
        const f16* fp = fk + (size_t)(b * N + i0 + f * 16 + li) * FKD + lg * 8;
#pragma unroll
        for (int ks = 0; ks < 4; ++ks) fb[f][ks] = *(const f16x8*)(fp + ks * 32);
    }

    // staging geometry: 512 thr x 64B = 32KB tile; row = tid>>2, 4 granules each
    const int sr  = tid >> 2;
    const int sg  = (tid & 3) * 4;
    const int ssw = sr & 7;
    {   // prologue: stage tile 0 -> kbuf[0]
        const f16* src = fk + (size_t)(b * N + sr) * FKD + CQ + (tid & 3) * 32;
#pragma unroll
        for (int k = 0; k < 4; ++k) {
            f16x8 vv = *(const f16x8*)(src + k * 8);
            *(f16x8*)(&kbuf[0][sr * 128 + ((sg + k) ^ ssw) * 8]) = vv;
        }
    }

    const f16* vbase = v + (size_t)(b * C + c0 + li) * N + lg * 8;
    f32x4 oacc[4][2] = {};
    float ms0 = -1e30f, ms1 = -1e30f, ls0 = 0.f, ls1 = 0.f;
    __syncthreads();

    for (int t = 0; t < 32; ++t) {
        const f16* kc = &kbuf[t & 1][0];
        f16*       kn = &kbuf[(t + 1) & 1][0];
        const int j0 = t * 128;
        // (a) issue next K-tile global loads early (T14 issue-early/write-late)
        const int jn = (t < 31) ? (t + 1) * 128 : 0;
        const f16* ssrc = fk + (size_t)(b * N + jn + sr) * FKD + CQ + (tid & 3) * 32;
        f16x8 stg[4];
#pragma unroll
        for (int k = 0; k < 4; ++k) stg[k] = *(const f16x8*)(ssrc + k * 8);

        // (b) QK for this wave's 16-j slice: S^T = mfma(A=K, B=F)
        f16x8 kf4[4];
#pragma unroll
        for (int ks = 0; ks < 4; ++ks)
            kf4[ks] = *(const f16x8*)(&kc[(wv * 16 + li) * 128 + ((ks * 4 + lg) ^ swl) * 8]);
        f32x4 s0 = {}, s1 = {};
#pragma unroll
        for (int ks = 0; ks < 4; ++ks) {
            s0 = __builtin_amdgcn_mfma_f32_16x16x32_f16(kf4[ks], fb[0][ks], s0, 0, 0, 0);
            s1 = __builtin_amdgcn_mfma_f32_16x16x32_f16(kf4[ks], fb[1][ks], s1, 0, 0, 0);
        }
        // (c) wave-local max per query i=li (rows j = wv*16 + lg*4 + r)
        float t0 = fmaxf(fmaxf(s0[0], s0[1]), fmaxf(s0[2], s0[3]));
        float t1 = fmaxf(fmaxf(s1[0], s1[1]), fmaxf(s1[2], s1[3]));
        t0 = fmaxf(t0, __shfl_xor(t0, 16)); t0 = fmaxf(t0, __shfl_xor(t0, 32));
        t1 = fmaxf(t1, __shfl_xor(t1, 16)); t1 = fmaxf(t1, __shfl_xor(t1, 32));
        if (lane < 16) { smax[wv][0][li] = t0; smax[wv][1][li] = t1; }
        __syncthreads();   // B1: max stats visible
        // (d) tile max over 8 waves (broadcast reads)
        float tm0 = smax[0][0][li], tm1 = smax[0][1][li];
#pragma unroll
        for (int w = 1; w < 8; ++w) { tm0 = fmaxf(tm0, smax[w][0][li]); tm1 = fmaxf(tm1, smax[w][1][li]); }
        // V prefetch for PV kf=0 (latency hides under softmax)
        f16x8 va[2][4];
#pragma unroll
        for (int cf = 0; cf < 4; ++cf) va[0][cf] = *(const f16x8*)(vbase + (size_t)(cf * 16) * N + j0);
        // T13 deferred rescale (identical decision in all waves: shared stats)
        if (!__all(tm0 <= ms0 + 8.0f)) {
            float mn = fmaxf(ms0, tm0), sc = __expf(ms0 - mn); ms0 = mn; ls0 *= sc;
#pragma unroll
            for (int cf = 0; cf < 4; ++cf) oacc[cf][0] *= sc;
        }
        if (!__all(tm1 <= ms1 + 8.0f)) {
            float mn = fmaxf(ms1, tm1), sc = __expf(ms1 - mn); ms1 = mn; ls1 *= sc;
#pragma unroll
            for (int cf = 0; cf < 4; ++cf) oacc[cf][1] *= sc;
        }
        // exp (only this wave's 4 j per lane per f) + P write + partial sums
        float ps0 = 0.f, ps1 = 0.f;
        f16x4 pk0, pk1;
#pragma unroll
        for (int r = 0; r < 4; ++r) { float p = __expf(s0[r] - ms0); ps0 += p; pk0[r] = (f16)p; }
#pragma unroll
        for (int r = 0; r < 4; ++r) { float p = __expf(s1[r] - ms1); ps1 += p; pk1[r] = (f16)p; }
        {   // P[i][j] f16, byte-granule swizzle ^ (i&7); j base = wv*16 + lg*4
            const int jl = wv * 16 + lg * 4;
            const int g  = (jl >> 3) ^ swl;
            *(f16x4*)(&pbuf[li * 128 + g * 8 + (jl & 7)]) = pk0;
            *(f16x4*)(&pbuf[(16 + li) * 128 + g * 8 + (jl & 7)]) = pk1;
        }
        ps0 += __shfl_xor(ps0, 16); ps0 += __shfl_xor(ps0, 32);
        ps1 += __shfl_xor(ps1, 16); ps1 += __shfl_xor(ps1, 32);
        if (lane < 16) { ssum[wv][0][li] = ps0; ssum[wv][1][li] = ps1; }
        // V prefetch for kf=1
#pragma unroll
        for (int cf = 0; cf < 4; ++cf) va[1][cf] = *(const f16x8*)(vbase + (size_t)(cf * 16) * N + j0 + 32);
        // write staged K tile to next buffer (loads issued at (a) have drained by now)
#pragma unroll
        for (int k = 0; k < 4; ++k)
            *(f16x8*)(&kn[sr * 128 + ((sg + k) ^ ssw) * 8]) = stg[k];
        __syncthreads();   // B2: P + ssum + next-K visible
        // (f) accumulate l from shared partial sums
        float a0 = 0.f, a1 = 0.f;
#pragma unroll
        for (int w = 0; w < 8; ++w) { a0 += ssum[w][0][li]; a1 += ssum[w][1][li]; }
        ls0 += a0; ls1 += a1;
        // (g) PV over full 128 j, this wave's 64 channels; rolling V prefetch
#pragma unroll
        for (int kf = 0; kf < 4; ++kf) {
            const int cur = kf & 1;
            const int g = (kf * 4 + lg) ^ swl;
            f16x8 pb0 = *(const f16x8*)(&pbuf[li * 128 + g * 8]);
            f16x8 pb1 = *(const f16x8*)(&pbuf[(16 + li) * 128 + g * 8]);
            f16x8 vv0 = va[cur][0], vv1 = va[cur][1], vv2 = va[cur][2], vv3 = va[cur][3];
            if (kf < 2) {
#pragma unroll
                for (int cf = 0; cf < 4; ++cf)
                    va[cur][cf] = *(const f16x8*)(vbase + (size_t)(cf * 16) * N + j0 + (kf + 2) * 32);
            }
            oacc[0][0] = __builtin_amdgcn_mfma_f32_16x16x32_f16(vv0, pb0, oacc[0][0], 0, 0, 0);
            oacc[0][1] = __builtin_amdgcn_mfma_f32_16x16x32_f16(vv0, pb1, oacc[0][1], 0, 0, 0);
            oacc[1][0] = __builtin_amdgcn_mfma_f32_16x16x32_f16(vv1, pb0, oacc[1][0], 0, 0, 0);
            oacc[1][1] = __builtin_amdgcn_mfma_f32_16x16x32_f16(vv1, pb1, oacc[1][1], 0, 0, 0);
            oacc[2][0] = __builtin_amdgcn_mfma_f32_16x16x32_f16(vv2, pb0, oacc[2][0], 0, 0, 0);
            oacc[2][1] = __builtin_amdgcn_mfma_f32_16x16x32_f16(vv2, pb1, oacc[2][1], 0, 0, 0);
            oacc[3][0] = __builtin_amdgcn_mfma_f32_16x16x32_f16(vv3, pb0, oacc[3][0], 0, 0, 0);
            oacc[3][1] = __builtin_amdgcn_mfma_f32_16x16x32_f16(vv3, pb1, oacc[3][1], 0, 0, 0);
        }
        // no 3rd barrier: next iter's B1 orders pbuf/kbuf reuse
    }

    // epilogue: O[c][i], i coalesced over li; + residual
    const float alpha = alphap[0];
    const float inv0 = alpha / ls0, inv1 = alpha / ls1;
#pragma unroll
    for (int f = 0; f < 2; ++f) {
        const float invf = f ? inv1 : inv0;
        const float* xp = x + (size_t)(b * C + c0) * N + i0 + f * 16 + li;
        float* op = out + (size_t)(b * C + c0) * N + i0 + f * 16 + li;
#pragma unroll
        for (int cf = 0; cf < 4; ++cf)
#pragma unroll
            for (int r = 0; r < 4; ++r) {
                const int cl = cf * 16 + lg * 4 + r;
                float o = f ? oacc[cf][1][r] : oacc[cf][0][r];
                op[(size_t)cl * N] = o * invf + xp[(size_t)cl * N];
            }
    }
}

extern "C" void kernel_launch(void* const* d_in, const int* in_sizes, int n_in,
                              void* d_out, int out_size, void* d_ws, size_t ws_size,
                              hipStream_t stream) {
    const float* x     = (const float*)d_in[0];
    const float* Wf_w  = (const float*)d_in[1];
    const float* Wf_b  = (const float*)d_in[2];
    const float* Wh_w  = (const float*)d_in[3];
    const float* Wh_b  = (const float*)d_in[4];
    const float* Wl_w  = (const float*)d_in[5];
    const float* Wl_b  = (const float*)d_in[6];
    const float* alpha = (const float*)d_in[7];
    char* ws = (char*)d_ws;
    f16*   xt   = (f16*)(ws + WS_XT);
    f16*   fkb  = (f16*)(ws + WS_FK);
    f16*   vb   = (f16*)(ws + WS_V);
    f16*   wcat = (f16*)(ws + WS_WCAT);
    f16*   wl   = (f16*)(ws + WS_WL);
    float* bcat = (float*)(ws + WS_BC);
    float* out  = (float*)d_out;

    prep_weights<<<dim3((C * C + 255) / 256), dim3(256), 0, stream>>>(Wf_w, Wf_b, Wh_w, Wh_b, Wl_w, wcat, wl, bcat);
    transpose_x<<<dim3(BATCH * 8 * 64), dim3(256), 0, stream>>>(x, xt);
    proj_fk<<<dim3(1024), dim3(256), 0, stream>>>(xt, wcat, bcat, fkb);
    proj_v<<<dim3(2048), dim3(256), 0, stream>>>(xt, wl, Wl_b, vb);
    // 4 b x 128 query-tiles(32q) = 512 blocks x 8 waves = 2 blocks/CU
    attn<<<dim3(512), dim3(512), 0, stream>>>(fkb, vb, x, alpha, out);
}

// Round 4
// 279.234 us; speedup vs baseline: 3.8218x; 1.7493x over previous
//
#include <hip/hip_runtime.h>
#include <hip/hip_bf16.h>

typedef _Float16 f16;
typedef _Float16 f16x4 __attribute__((ext_vector_type(4)));
typedef _Float16 f16x8 __attribute__((ext_vector_type(8)));
typedef float f32x4 __attribute__((ext_vector_type(4)));

constexpr int BATCH = 4, C = 512, CQ = 128, N = 4096;
constexpr int FKD = 256; // f(128) + k(128) channels, stacked

// workspace layout (bytes)
constexpr size_t WS_XT   = 0;                                      // f16 [B][N][C]   16 MB
constexpr size_t WS_FK   = WS_XT   + (size_t)BATCH * N * C * 2;    // f16 [B][N][256]  8 MB
constexpr size_t WS_V    = WS_FK   + (size_t)BATCH * N * FKD * 2;  // f16 [B][C][N]   16 MB
constexpr size_t WS_WCAT = WS_V    + (size_t)BATCH * C * N * 2;    // f16 [256][512]
constexpr size_t WS_WL   = WS_WCAT + (size_t)FKD * C * 2;          // f16 [512][512]
constexpr size_t WS_BC   = WS_WL   + (size_t)C * C * 2;            // f32 [256]

// ---------------------------------------------------------------- weights->fp16
__global__ void prep_weights(const float* __restrict__ Wf_w, const float* __restrict__ Wf_b,
                             const float* __restrict__ Wh_w, const float* __restrict__ Wh_b,
                             const float* __restrict__ Wl_w,
                             f16* __restrict__ wcat, f16* __restrict__ wl, float* __restrict__ bcat) {
    int i = blockIdx.x * 256 + threadIdx.x;                 // grid covers C*C
    if (i < FKD * C) {
        int o = i >> 9, c = i & 511;
        float v = (o < CQ) ? Wf_w[o * C + c] : Wh_w[(o - CQ) * C + c];
        wcat[i] = (f16)v;
    }
    if (i < C * C) wl[i] = (f16)Wl_w[i];
    if (i < FKD) bcat[i] = (i < CQ) ? Wf_b[i] : Wh_b[i - CQ];
}

// ---------------------------------------------------------------- x (B,C,N) f32 -> xT (B,N,C) f16
__global__ void transpose_x(const float* __restrict__ x, f16* __restrict__ xt) {
    __shared__ float tile[64][65];
    int gid = blockIdx.x;
    int b = gid >> 9, rem = gid & 511;
    int c0 = (rem >> 6) * 64, n0 = (rem & 63) * 64;
    int t = threadIdx.x;
    int tn = t & 63, tg = t >> 6;
    const float* xp = x + (size_t)b * C * N + (size_t)c0 * N + n0;
#pragma unroll
    for (int r = 0; r < 16; ++r) {
        int cl = tg + r * 4;
        tile[cl][tn] = xp[(size_t)cl * N + tn];
    }
    __syncthreads();
    f16* xo = xt + (size_t)b * N * C + (size_t)n0 * C + c0;
#pragma unroll
    for (int r = 0; r < 16; ++r) {
        int nl = tg + r * 4;
        xo[(size_t)nl * C + tn] = (f16)tile[tn][nl];
    }
}

// ---------------------------------------------------------------- FK projection: FK[b][n][o] = (Wcat @ x[:,n]) + bcat
__global__ void __launch_bounds__(256) proj_fk(const f16* __restrict__ xt, const f16* __restrict__ wcat,
                                               const float* __restrict__ bcat, f16* __restrict__ fk) {
    int wid = blockIdx.x * 4 + (threadIdx.x >> 6);
    int lane = threadIdx.x & 63;
    int li = lane & 15, lg = lane >> 4;
    int b  = wid >> 10;
    int nt = (wid >> 2) & 255;
    int ot = wid & 3;
    int n0 = nt * 16, o0 = ot * 64;
    const f16* ap = xt + (size_t)(b * N + n0 + li) * C + lg * 8;
    const f16* bp = wcat + (size_t)o0 * C + lg * 8;
    f32x4 acc[4] = {};
    for (int ks = 0; ks < 16; ++ks) {
        f16x8 a = *(const f16x8*)(ap + ks * 32);
#pragma unroll
        for (int t = 0; t < 4; ++t) {
            f16x8 bb = *(const f16x8*)(bp + (size_t)(t * 16 + li) * C + ks * 32);
            acc[t] = __builtin_amdgcn_mfma_f32_16x16x32_f16(a, bb, acc[t], 0, 0, 0);
        }
    }
#pragma unroll
    for (int t = 0; t < 4; ++t) {
        int o = o0 + t * 16 + li;
        float bias = bcat[o];
#pragma unroll
        for (int r = 0; r < 4; ++r) {
            int n = n0 + lg * 4 + r;
            fk[(size_t)(b * N + n) * FKD + o] = (f16)(acc[t][r] + bias);
        }
    }
}

// ---------------------------------------------------------------- V projection: V[b][c][n] = (Wl @ x[:,n]) + Wl_b
__global__ void __launch_bounds__(256) proj_v(const f16* __restrict__ xt, const f16* __restrict__ wl,
                                              const float* __restrict__ wlb, f16* __restrict__ v) {
    int wid = blockIdx.x * 4 + (threadIdx.x >> 6);
    int lane = threadIdx.x & 63;
    int li = lane & 15, lg = lane >> 4;
    int b  = wid >> 11;
    int ct = (wid >> 6) & 31;
    int nt = wid & 63;
    int c0 = ct * 16, n0 = nt * 64;
    const f16* ap = wl + (size_t)(c0 + li) * C + lg * 8;
    const f16* bp = xt + (size_t)(b * N + n0) * C + lg * 8;
    f32x4 acc[4] = {};
    for (int ks = 0; ks < 16; ++ks) {
        f16x8 a = *(const f16x8*)(ap + ks * 32);
#pragma unroll
        for (int t = 0; t < 4; ++t) {
            f16x8 bb = *(const f16x8*)(bp + (size_t)(t * 16 + li) * C + ks * 32);
            acc[t] = __builtin_amdgcn_mfma_f32_16x16x32_f16(a, bb, acc[t], 0, 0, 0);
        }
    }
#pragma unroll
    for (int t = 0; t < 4; ++t) {
#pragma unroll
        for (int r = 0; r < 4; ++r) {
            int c = c0 + lg * 4 + r;
            int n = n0 + t * 16 + li;
            v[(size_t)(b * C + c) * N + n] = (f16)(acc[t][r] + wlb[c]);
        }
    }
}

// ---------------------------------------------------------------- flash attention + residual (v4)
// Block = 8 waves (512 thr), one 64-query tile; wave w owns c-slice [w*64, w*64+64),
// 4 i-frags. KVBLK=128 K tile LDS double-buffered + swizzled; QK computed once
// (wave w does its 16-j slice for all 4 i-frags); P[64][128] f16 shared.
// Grid 256 = 1 block/CU; XCD-pinning decode keeps ONE batch per XCD (L2-resident V).
__global__ void __launch_bounds__(512, 2) attn(const f16* __restrict__ fk, const f16* __restrict__ v,
                                               const float* __restrict__ x, const float* __restrict__ alphap,
                                               float* __restrict__ out) {
    __shared__ __align__(16) f16 kbuf[2][128 * 128];   // 64 KB K tile, double-buffered
    __shared__ __align__(16) f16 pbuf[64 * 128];       // 16 KB shared P
    __shared__ float smax[8][4][16];
    __shared__ float ssum[8][4][16];

    const int tid  = threadIdx.x;
    const int wv   = tid >> 6;
    const int lane = tid & 63;
    const int li = lane & 15, lg = lane >> 4;
    const int swl = li & 7;
    // XCD-pinning: under blk%8 round-robin, each XCD sees a single batch
    const int v0 = blockIdx.x;
    const int b  = (v0 & 7) >> 1;
    const int it = ((v0 & 1) << 5) | (v0 >> 3);
    const int i0 = it * 64;
    const int c0 = wv * 64;

    // F fragments (B operand of swapped QK): col=i, k=ck; 4 i-frags
    f16x8 fb[4][4];
#pragma unroll
    for (int f = 0; f < 4; ++f) {
        const f16* fp = fk + (size_t)(b * N + i0 + f * 16 + li) * FKD + lg * 8;
#pragma unroll
        for (int ks = 0; ks < 4; ++ks) fb[f][ks] = *(const f16x8*)(fp + ks * 32);
    }

    // staging geometry: 512 thr x 64B = 32KB tile; row = tid>>2, 4 granules each
    const int sr  = tid >> 2;
    const int sg  = (tid & 3) * 4;
    const int ssw = sr & 7;
    {   // prologue: stage tile 0 -> kbuf[0]
        const f16* src = fk + (size_t)(b * N + sr) * FKD + CQ + (tid & 3) * 32;
#pragma unroll
        for (int k = 0; k < 4; ++k) {
            f16x8 vv = *(const f16x8*)(src + k * 8);
            *(f16x8*)(&kbuf[0][sr * 128 + ((sg + k) ^ ssw) * 8]) = vv;
        }
    }

    const f16* vbase = v + (size_t)(b * C + c0 + li) * N + lg * 8;
    f32x4 oacc[4][4] = {};                       // [c-frag][i-frag]
    float ms[4] = {-1e30f, -1e30f, -1e30f, -1e30f};
    float ls[4] = {0.f, 0.f, 0.f, 0.f};
    __syncthreads();

    for (int t = 0; t < 32; ++t) {
        const f16* kc = &kbuf[t & 1][0];
        f16*       kn = &kbuf[(t + 1) & 1][0];
        const int j0 = t * 128;
        // (a) issue next K-tile global loads early (T14 issue-early/write-late)
        const int jn = (t < 31) ? (t + 1) * 128 : 0;
        const f16* ssrc = fk + (size_t)(b * N + jn + sr) * FKD + CQ + (tid & 3) * 32;
        f16x8 stg[4];
#pragma unroll
        for (int k = 0; k < 4; ++k) stg[k] = *(const f16x8*)(ssrc + k * 8);

        // (b) QK for this wave's 16-j slice, all 4 i-frags
        f16x8 kf4[4];
#pragma unroll
        for (int ks = 0; ks < 4; ++ks)
            kf4[ks] = *(const f16x8*)(&kc[(wv * 16 + li) * 128 + ((ks * 4 + lg) ^ swl) * 8]);
        f32x4 s[4] = {};
        __builtin_amdgcn_s_setprio(1);
#pragma unroll
        for (int ks = 0; ks < 4; ++ks)
#pragma unroll
            for (int f = 0; f < 4; ++f)
                s[f] = __builtin_amdgcn_mfma_f32_16x16x32_f16(kf4[ks], fb[f][ks], s[f], 0, 0, 0);
        __builtin_amdgcn_s_setprio(0);

        // (c) wave-local max per query (rows j = wv*16 + lg*4 + r)
        float tm[4];
#pragma unroll
        for (int f = 0; f < 4; ++f) {
            float t0 = fmaxf(fmaxf(s[f][0], s[f][1]), fmaxf(s[f][2], s[f][3]));
            t0 = fmaxf(t0, __shfl_xor(t0, 16));
            t0 = fmaxf(t0, __shfl_xor(t0, 32));
            tm[f] = t0;
        }
        if (lane < 16) {
#pragma unroll
            for (int f = 0; f < 4; ++f) smax[wv][f][li] = tm[f];
        }
        // V prefetch for PV kf=0, issued before the barrier (latency hides under it)
        f16x8 va[2][4];
#pragma unroll
        for (int cf = 0; cf < 4; ++cf) va[0][cf] = *(const f16x8*)(vbase + (size_t)(cf * 16) * N + j0);
        __syncthreads();   // B1: max stats visible
        // (d) tile max over 8 waves (broadcast reads)
        float gm[4];
#pragma unroll
        for (int f = 0; f < 4; ++f) {
            float m0 = smax[0][f][li];
#pragma unroll
            for (int w = 1; w < 8; ++w) m0 = fmaxf(m0, smax[w][f][li]);
            gm[f] = m0;
        }
        // V prefetch for kf=1
#pragma unroll
        for (int cf = 0; cf < 4; ++cf) va[1][cf] = *(const f16x8*)(vbase + (size_t)(cf * 16) * N + j0 + 32);
        // T13 deferred rescale (identical decision in all waves: shared stats)
#pragma unroll
        for (int f = 0; f < 4; ++f) {
            if (!__all(gm[f] <= ms[f] + 8.0f)) {
                float mn = fmaxf(ms[f], gm[f]), sc = __expf(ms[f] - mn);
                ms[f] = mn; ls[f] *= sc;
#pragma unroll
                for (int cf = 0; cf < 4; ++cf) oacc[cf][f] *= sc;
            }
        }
        // exp (this wave's 4 j per lane per f) + P write + partial sums
        const int jl = wv * 16 + lg * 4;
        const int gg = (jl >> 3) ^ swl;
        float ps[4];
#pragma unroll
        for (int f = 0; f < 4; ++f) {
            f16x4 pk;
            float p0 = 0.f;
#pragma unroll
            for (int r = 0; r < 4; ++r) { float p = __expf(s[f][r] - ms[f]); p0 += p; pk[r] = (f16)p; }
            *(f16x4*)(&pbuf[(f * 16 + li) * 128 + gg * 8 + (jl & 7)]) = pk;
            ps[f] = p0;
        }
#pragma unroll
        for (int f = 0; f < 4; ++f) {
            ps[f] += __shfl_xor(ps[f], 16);
            ps[f] += __shfl_xor(ps[f], 32);
        }
        if (lane < 16) {
#pragma unroll
            for (int f = 0; f < 4; ++f) ssum[wv][f][li] = ps[f];
        }
        // write staged K tile to next buffer (loads from (a) drained by now)
#pragma unroll
        for (int k = 0; k < 4; ++k)
            *(f16x8*)(&kn[sr * 128 + ((sg + k) ^ ssw) * 8]) = stg[k];
        __syncthreads();   // B2: P + ssum + next-K visible
        // (f) accumulate l from shared partial sums
#pragma unroll
        for (int f = 0; f < 4; ++f) {
            float a0 = 0.f;
#pragma unroll
            for (int w = 0; w < 8; ++w) a0 += ssum[w][f][li];
            ls[f] += a0;
        }
        // (g) PV over full 128 j, this wave's 64 channels; rolling V prefetch
#pragma unroll
        for (int kf = 0; kf < 4; ++kf) {
            const int cur = kf & 1;
            const int g = (kf * 4 + lg) ^ swl;
            f16x8 pb[4];
#pragma unroll
            for (int f = 0; f < 4; ++f)
                pb[f] = *(const f16x8*)(&pbuf[(f * 16 + li) * 128 + g * 8]);
            f16x8 vv0 = va[cur][0], vv1 = va[cur][1], vv2 = va[cur][2], vv3 = va[cur][3];
            if (kf < 2) {
#pragma unroll
                for (int cf = 0; cf < 4; ++cf)
                    va[cur][cf] = *(const f16x8*)(vbase + (size_t)(cf * 16) * N + j0 + (kf + 2) * 32);
            }
            __builtin_amdgcn_s_setprio(1);
#pragma unroll
            for (int f = 0; f < 4; ++f) {
                oacc[0][f] = __builtin_amdgcn_mfma_f32_16x16x32_f16(vv0, pb[f], oacc[0][f], 0, 0, 0);
                oacc[1][f] = __builtin_amdgcn_mfma_f32_16x16x32_f16(vv1, pb[f], oacc[1][f], 0, 0, 0);
                oacc[2][f] = __builtin_amdgcn_mfma_f32_16x16x32_f16(vv2, pb[f], oacc[2][f], 0, 0, 0);
                oacc[3][f] = __builtin_amdgcn_mfma_f32_16x16x32_f16(vv3, pb[f], oacc[3][f], 0, 0, 0);
            }
            __builtin_amdgcn_s_setprio(0);
        }
        // no 3rd barrier: next iter's B1 orders pbuf/kbuf reuse
    }

    // epilogue: O[c][i], i coalesced over li; + residual
    const float alpha = alphap[0];
#pragma unroll
    for (int f = 0; f < 4; ++f) {
        const float invf = alpha / ls[f];
        const float* xp = x + (size_t)(b * C + c0) * N + i0 + f * 16 + li;
        float* op = out + (size_t)(b * C + c0) * N + i0 + f * 16 + li;
#pragma unroll
        for (int cf = 0; cf < 4; ++cf)
#pragma unroll
            for (int r = 0; r < 4; ++r) {
                const int cl = cf * 16 + lg * 4 + r;
                op[(size_t)cl * N] = oacc[cf][f][r] * invf + xp[(size_t)cl * N];
            }
    }
}

extern "C" void kernel_launch(void* const* d_in, const int* in_sizes, int n_in,
                              void* d_out, int out_size, void* d_ws, size_t ws_size,
                              hipStream_t stream) {
    const float* x     = (const float*)d_in[0];
    const float* Wf_w  = (const float*)d_in[1];
    const float* Wf_b  = (const float*)d_in[2];
    const float* Wh_w  = (const float*)d_in[3];
    const float* Wh_b  = (const float*)d_in[4];
    const float* Wl_w  = (const float*)d_in[5];
    const float* Wl_b  = (const float*)d_in[6];
    const float* alpha = (const float*)d_in[7];
    char* ws = (char*)d_ws;
    f16*   xt   = (f16*)(ws + WS_XT);
    f16*   fkb  = (f16*)(ws + WS_FK);
    f16*   vb   = (f16*)(ws + WS_V);
    f16*   wcat = (f16*)(ws + WS_WCAT);
    f16*   wl   = (f16*)(ws + WS_WL);
    float* bcat = (float*)(ws + WS_BC);
    float* out  = (float*)d_out;

    prep_weights<<<dim3((C * C + 255) / 256), dim3(256), 0, stream>>>(Wf_w, Wf_b, Wh_w, Wh_b, Wl_w, wcat, wl, bcat);
    transpose_x<<<dim3(BATCH * 8 * 64), dim3(256), 0, stream>>>(x, xt);
    proj_fk<<<dim3(1024), dim3(256), 0, stream>>>(xt, wcat, bcat, fkb);
    proj_v<<<dim3(2048), dim3(256), 0, stream>>>(xt, wl, Wl_b, vb);
    // 4 b x 64 query-tiles(64q) = 256 blocks x 8 waves = 1 block/CU, XCD-pinned
    attn<<<dim3(256), dim3(512), 0, stream>>>(fkb, vb, x, alpha, out);
}